// Round 2
// baseline (1501.152 us; speedup 1.0000x reference)
//
#include <hip/hip_runtime.h>
#include <stdint.h>
#include <stddef.h>

// MatchLSTMAttention: B=64, T=2048, inp_p=inp_q=out=512
// out[b] = concat(input_p[b], z[b]); z = softmax_t(w . tanh(prq[b] + iq[b,t] @ Wq^T) + match_b) @ iq[b]

typedef __attribute__((ext_vector_type(8))) short short8;
typedef __attribute__((ext_vector_type(8))) unsigned short ushort8v;
typedef __attribute__((ext_vector_type(4))) float f32x4;

__device__ __forceinline__ unsigned short f2bf(float f) {
    unsigned int u = __builtin_bit_cast(unsigned int, f);
    return (unsigned short)((u + 0x7FFFu + ((u >> 16) & 1u)) >> 16);  // RNE
}

__device__ __forceinline__ void gload_lds16(const void* g, void* l) {
    __builtin_amdgcn_global_load_lds(
        (const __attribute__((address_space(1))) unsigned int*)g,
        (__attribute__((address_space(3))) unsigned int*)l, 16, 0, 0);
}

// ---------- kernel 0: Wq fp32 -> bf16 ----------
__global__ __launch_bounds__(256) void k_convert(const float* __restrict__ Wq,
                                                 unsigned short* __restrict__ Wq_bf) {
    int i = (blockIdx.x * 256 + threadIdx.x) * 8;
    float4 a = *(const float4*)(Wq + i);
    float4 b = *(const float4*)(Wq + i + 4);
    ushort8v o;
    o[0] = f2bf(a.x); o[1] = f2bf(a.y); o[2] = f2bf(a.z); o[3] = f2bf(a.w);
    o[4] = f2bf(b.x); o[5] = f2bf(b.y); o[6] = f2bf(b.z); o[7] = f2bf(b.w);
    *(ushort8v*)(Wq_bf + i) = o;
}

// ---------- kernel 1: prq[b,o] = ip.Wp^T + h.Wr^T + bp + bq + br ----------
__global__ __launch_bounds__(256) void k_prq(
        const float* __restrict__ ip, const float* __restrict__ h,
        const float* __restrict__ Wp, const float* __restrict__ Wr,
        const float* __restrict__ bp, const float* __restrict__ bq,
        const float* __restrict__ br, float* __restrict__ prq) {
    __shared__ float ip_lds[64][68];
    __shared__ float h_lds[64][68];
    __shared__ float wp_lds[8][68];
    __shared__ float wr_lds[8][68];
    const int tid = threadIdx.x;
    const int o0 = blockIdx.x * 8;
    const int bb = tid >> 3;
    const int oo = tid & 7;
    float acc0 = 0.f, acc1 = 0.f;
    const int lrow = tid >> 2;
    const int lcol = (tid & 3) * 16;
    for (int kc = 0; kc < 512; kc += 64) {
        #pragma unroll
        for (int j = 0; j < 16; j += 4) {
            float4 v = *(const float4*)(ip + lrow * 512 + kc + lcol + j);
            ip_lds[lrow][lcol + j] = v.x; ip_lds[lrow][lcol + j + 1] = v.y;
            ip_lds[lrow][lcol + j + 2] = v.z; ip_lds[lrow][lcol + j + 3] = v.w;
            float4 u = *(const float4*)(h + lrow * 512 + kc + lcol + j);
            h_lds[lrow][lcol + j] = u.x; h_lds[lrow][lcol + j + 1] = u.y;
            h_lds[lrow][lcol + j + 2] = u.z; h_lds[lrow][lcol + j + 3] = u.w;
        }
        if (tid < 128) {
            int r = tid >> 4, c = (tid & 15) * 4;
            float4 v = *(const float4*)(Wp + (size_t)(o0 + r) * 512 + kc + c);
            wp_lds[r][c] = v.x; wp_lds[r][c + 1] = v.y; wp_lds[r][c + 2] = v.z; wp_lds[r][c + 3] = v.w;
        } else {
            int t2 = tid - 128;
            int r = t2 >> 4, c = (t2 & 15) * 4;
            float4 v = *(const float4*)(Wr + (size_t)(o0 + r) * 512 + kc + c);
            wr_lds[r][c] = v.x; wr_lds[r][c + 1] = v.y; wr_lds[r][c + 2] = v.z; wr_lds[r][c + 3] = v.w;
        }
        __syncthreads();
        #pragma unroll 4
        for (int k = 0; k < 64; ++k) {
            float wpv = wp_lds[oo][k], wrv = wr_lds[oo][k];
            acc0 += ip_lds[bb][k] * wpv + h_lds[bb][k] * wrv;
            acc1 += ip_lds[bb + 32][k] * wpv + h_lds[bb + 32][k] * wrv;
        }
        __syncthreads();
    }
    const int o = o0 + oo;
    float base = bp[o] + bq[o] + br[o];
    prq[bb * 512 + o] = acc0 + base;
    prq[(bb + 32) * 512 + o] = acc1 + base;
}

// ---------- kernel 2: fused Gq GEMM + tanh + w-reduction -> logits[b,t] ----------
// BM=256 (flattened B*T rows), BN=512 (full N), BK=32, 16 waves (4m x 4n), wave tile 64x128.
// B via global_load_lds (linear dest + pre-swizzled source); A reg-staged fp32->bf16.
__global__ __launch_bounds__(1024, 8) void k_gq(
        const float* __restrict__ iq, const unsigned short* __restrict__ Wq_bf,
        const float* __restrict__ prq, const float* __restrict__ wv,
        const float* __restrict__ match_b, float* __restrict__ logits) {
    __shared__ unsigned short A_t[256][32];   // 16 KB, chunk ^= (row>>1)&3 swizzle
    __shared__ unsigned short B_t[512][32];   // 32 KB, same swizzle (via source pre-swizzle)
    __shared__ float w_lds[512];
    __shared__ float prq_lds[512];
    __shared__ float red[4][256];

    const int tid = threadIdx.x;
    const int m0 = blockIdx.x * 256;          // 512 blocks; block fully inside one b
    const int b = m0 >> 11;
    if (tid < 512) {
        w_lds[tid] = wv[tid];
        prq_lds[tid] = prq[b * 512 + tid];
    }

    const int lane = tid & 63;
    const int wave = tid >> 6;
    const int wm = wave >> 2;                 // 0..3
    const int wn = wave & 3;                  // 0..3
    const int r16 = lane & 15;
    const int cc = lane >> 4;                 // k-chunk 0..3 (8 bf16 = 16B)
    const int swz = ((cc ^ ((r16 >> 1) & 3)) << 3);  // read-side chunk offset (elements)

    // A staging: 256 rows x 32 k fp32; each thread: 8 floats -> 8 bf16 -> one ds_write_b128
    const int ar = tid >> 2;
    const int ag = tid & 3;                   // global k-chunk
    const int as = ag ^ ((ar >> 1) & 3);      // stored (swizzled) chunk
    const float* aptr = iq + (size_t)(m0 + ar) * 512 + ag * 8;
    unsigned short* adst = &A_t[ar][as * 8];

    // B staging: linear LDS dest (global_load_lds), source pre-swizzled so that
    // stored chunk s holds global chunk s ^ ((row>>1)&3).
    const int br = tid >> 2;                  // rows 0..255 (round 0), +256 (round 1)
    const int bg = (tid & 3) ^ ((br >> 1) & 3);
    const unsigned short* bsrc0 = Wq_bf + (size_t)br * 512 + bg * 8;
    const unsigned short* bsrc1 = bsrc0 + 256 * 512;        // rows 256..511, same swizzle phase
    unsigned short* bdst0 = ((unsigned short*)B_t) + wave * 512;   // wave-uniform, +lane*16B by HW
    unsigned short* bdst1 = bdst0 + 8192;                          // +16 KB

    f32x4 acc[4][8];
    #pragma unroll
    for (int i = 0; i < 4; ++i)
        #pragma unroll
        for (int j = 0; j < 8; ++j) acc[i][j] = (f32x4){0.f, 0.f, 0.f, 0.f};

    for (int k0 = 0; k0 < 512; k0 += 32) {
        gload_lds16(bsrc0 + k0, bdst0);
        gload_lds16(bsrc1 + k0, bdst1);
        float4 av0 = *(const float4*)(aptr + k0);
        float4 av1 = *(const float4*)(aptr + k0 + 4);
        ushort8v ap;
        ap[0] = f2bf(av0.x); ap[1] = f2bf(av0.y); ap[2] = f2bf(av0.z); ap[3] = f2bf(av0.w);
        ap[4] = f2bf(av1.x); ap[5] = f2bf(av1.y); ap[6] = f2bf(av1.z); ap[7] = f2bf(av1.w);
        *(ushort8v*)adst = ap;
        __syncthreads();

        short8 afr[4];
        #pragma unroll
        for (int mf = 0; mf < 4; ++mf)
            afr[mf] = *(const short8*)&A_t[wm * 64 + mf * 16 + r16][swz];
        #pragma unroll
        for (int nf = 0; nf < 8; ++nf) {
            short8 bfr = *(const short8*)&B_t[wn * 128 + nf * 16 + r16][swz];
            #pragma unroll
            for (int mf = 0; mf < 4; ++mf)
                acc[mf][nf] = __builtin_amdgcn_mfma_f32_16x16x32_bf16(afr[mf], bfr, acc[mf][nf], 0, 0, 0);
        }
        __syncthreads();
    }

    // epilogue: logit contribution = sum_cols w[c] * tanh(acc + prq[c])
    float part[4][4];
    #pragma unroll
    for (int mf = 0; mf < 4; ++mf)
        #pragma unroll
        for (int j = 0; j < 4; ++j) part[mf][j] = 0.f;

    #pragma unroll
    for (int nf = 0; nf < 8; ++nf) {
        int c = wn * 128 + nf * 16 + r16;
        float wc = w_lds[c];
        float pc = prq_lds[c];
        #pragma unroll
        for (int mf = 0; mf < 4; ++mf) {
            #pragma unroll
            for (int j = 0; j < 4; ++j) {
                float x = acc[mf][nf][j] + pc;
                float e = __expf(2.f * x);               // fast tanh: 1 - 2/(e^2x + 1)
                part[mf][j] += wc * (1.f - 2.f / (e + 1.f));
            }
        }
    }
    #pragma unroll
    for (int mf = 0; mf < 4; ++mf)
        #pragma unroll
        for (int j = 0; j < 4; ++j) {
            float v = part[mf][j];
            v += __shfl_xor(v, 1);
            v += __shfl_xor(v, 2);
            v += __shfl_xor(v, 4);
            v += __shfl_xor(v, 8);
            part[mf][j] = v;
        }
    if (r16 == 0) {
        #pragma unroll
        for (int mf = 0; mf < 4; ++mf)
            #pragma unroll
            for (int j = 0; j < 4; ++j)
                red[wn][wm * 64 + mf * 16 + cc * 4 + j] = part[mf][j];
    }
    __syncthreads();
    if (tid < 256)
        logits[m0 + tid] = red[0][tid] + red[1][tid] + red[2][tid] + red[3][tid] + match_b[0];
}

// ---------- kernel 3: softmax stats per b; copy input_p -> out; zero z ----------
__global__ __launch_bounds__(256) void k_stats(const float* __restrict__ logits,
                                               const float* __restrict__ ip,
                                               float* __restrict__ out,
                                               float* __restrict__ stats) {
    const int b = blockIdx.x, tid = threadIdx.x;
    __shared__ float sm[256];
    float m = -1e30f;
    for (int i = tid; i < 2048; i += 256) m = fmaxf(m, logits[b * 2048 + i]);
    sm[tid] = m;
    __syncthreads();
    for (int s = 128; s > 0; s >>= 1) {
        if (tid < s) sm[tid] = fmaxf(sm[tid], sm[tid + s]);
        __syncthreads();
    }
    float bmax = sm[0];
    __syncthreads();
    float ssum = 0.f;
    for (int i = tid; i < 2048; i += 256) ssum += __expf(logits[b * 2048 + i] - bmax);
    sm[tid] = ssum;
    __syncthreads();
    for (int s = 128; s > 0; s >>= 1) {
        if (tid < s) sm[tid] += sm[tid + s];
        __syncthreads();
    }
    if (tid == 0) { stats[b * 2] = bmax; stats[b * 2 + 1] = sm[0]; }
    out[b * 1024 + tid] = ip[b * 512 + tid];
    out[b * 1024 + 256 + tid] = ip[b * 512 + 256 + tid];
    out[b * 1024 + 512 + tid] = 0.f;
    out[b * 1024 + 768 + tid] = 0.f;
}

// ---------- kernel 4: z[b,q] += sum_t alpha[b,t] * iq[b,t,q] ----------
#define TC 128
__global__ __launch_bounds__(256) void k_z(const float* __restrict__ logits,
                                           const float* __restrict__ stats,
                                           const float* __restrict__ iq,
                                           float* __restrict__ out) {
    const int blk = blockIdx.x;
    const int b = blk >> 4;
    const int c = blk & 15;
    const int tid = threadIdx.x;
    __shared__ float al[TC];
    const float bmax = stats[b * 2];
    const float inv = 1.f / stats[b * 2 + 1];
    if (tid < TC) al[tid] = __expf(logits[b * 2048 + c * TC + tid] - bmax) * inv;
    __syncthreads();
    const int q = tid * 2;
    float ax = 0.f, ay = 0.f;
    const float* base = iq + ((size_t)b * 2048 + (size_t)c * TC) * 512 + q;
    #pragma unroll 4
    for (int t = 0; t < TC; ++t) {
        float2 v = *(const float2*)(base + (size_t)t * 512);
        float a = al[t];
        ax += a * v.x;
        ay += a * v.y;
    }
    atomicAdd(&out[b * 1024 + 512 + q], ax);
    atomicAdd(&out[b * 1024 + 512 + q + 1], ay);
}

extern "C" void kernel_launch(void* const* d_in, const int* in_sizes, int n_in,
                              void* d_out, int out_size, void* d_ws, size_t ws_size,
                              hipStream_t stream) {
    const float* input_p = (const float*)d_in[0];
    const float* input_q = (const float*)d_in[1];
    const float* h_tm1   = (const float*)d_in[2];
    const float* Wp      = (const float*)d_in[3];
    const float* bp      = (const float*)d_in[4];
    const float* Wq      = (const float*)d_in[5];
    const float* bq      = (const float*)d_in[6];
    const float* Wr      = (const float*)d_in[7];
    const float* br      = (const float*)d_in[8];
    const float* wv      = (const float*)d_in[9];
    const float* match_b = (const float*)d_in[10];
    float* out = (float*)d_out;

    char* ws = (char*)d_ws;
    unsigned short* Wq_bf = (unsigned short*)ws;            // 512 KB
    float* prq    = (float*)(ws + 512 * 1024);              // 128 KB
    float* logits = (float*)(ws + 640 * 1024);              // 512 KB
    float* stats  = (float*)(ws + 1152 * 1024);             // 512 B

    k_convert<<<dim3(128), dim3(256), 0, stream>>>(Wq, Wq_bf);
    k_prq<<<dim3(64), dim3(256), 0, stream>>>(input_p, h_tm1, Wp, Wr, bp, bq, br, prq);
    k_gq<<<dim3(512), dim3(1024), 0, stream>>>(input_q, Wq_bf, prq, wv, match_b, logits);
    k_stats<<<dim3(64), dim3(256), 0, stream>>>(logits, input_p, out, stats);
    k_z<<<dim3(64 * 16), dim3(256), 0, stream>>>(logits, stats, input_q, out);
}

// Round 3
// 218.970 us; speedup vs baseline: 6.8555x; 6.8555x over previous
//
#include <hip/hip_runtime.h>
#include <stdint.h>
#include <stddef.h>

// MatchLSTMAttention: B=64, T=2048, inp_p=inp_q=out=512
// out[b] = concat(input_p[b], z[b]); z = softmax_t(w . tanh(prq[b] + iq[b,t] @ Wq^T)) @ iq[b]
// (match_b dropped: softmax is shift-invariant)

typedef __attribute__((ext_vector_type(8))) short short8;
typedef __attribute__((ext_vector_type(8))) unsigned short ushort8v;
typedef __attribute__((ext_vector_type(4))) float f32x4;

__device__ __forceinline__ unsigned short f2bf(float f) {
    unsigned int u = __builtin_bit_cast(unsigned int, f);
    return (unsigned short)((u + 0x7FFFu + ((u >> 16) & 1u)) >> 16);  // RNE
}

__device__ __forceinline__ void gload_lds16(const void* g, void* l) {
    __builtin_amdgcn_global_load_lds(
        (const __attribute__((address_space(1))) unsigned int*)g,
        (__attribute__((address_space(3))) unsigned int*)l, 16, 0, 0);
}

// ---------- kernel Z: zero logits ----------
__global__ __launch_bounds__(256) void k_zero(float* __restrict__ p) {
    int i = (blockIdx.x * 256 + threadIdx.x) * 4;
    *(float4*)(p + i) = make_float4(0.f, 0.f, 0.f, 0.f);
}

// ---------- kernel 0: Wq fp32 -> bf16 ----------
__global__ __launch_bounds__(256) void k_convert(const float* __restrict__ Wq,
                                                 unsigned short* __restrict__ Wq_bf) {
    int i = (blockIdx.x * 256 + threadIdx.x) * 8;
    float4 a = *(const float4*)(Wq + i);
    float4 b = *(const float4*)(Wq + i + 4);
    ushort8v o;
    o[0] = f2bf(a.x); o[1] = f2bf(a.y); o[2] = f2bf(a.z); o[3] = f2bf(a.w);
    o[4] = f2bf(b.x); o[5] = f2bf(b.y); o[6] = f2bf(b.z); o[7] = f2bf(b.w);
    *(ushort8v*)(Wq_bf + i) = o;
}

// ---------- kernel 1: prq[b,o] = ip.Wp^T + h.Wr^T + bp + bq + br ----------
__global__ __launch_bounds__(256) void k_prq(
        const float* __restrict__ ip, const float* __restrict__ h,
        const float* __restrict__ Wp, const float* __restrict__ Wr,
        const float* __restrict__ bp, const float* __restrict__ bq,
        const float* __restrict__ br, float* __restrict__ prq) {
    __shared__ float ip_lds[64][68];
    __shared__ float h_lds[64][68];
    __shared__ float wp_lds[8][68];
    __shared__ float wr_lds[8][68];
    const int tid = threadIdx.x;
    const int o0 = blockIdx.x * 8;
    const int bb = tid >> 3;
    const int oo = tid & 7;
    float acc0 = 0.f, acc1 = 0.f;
    const int lrow = tid >> 2;
    const int lcol = (tid & 3) * 16;
    for (int kc = 0; kc < 512; kc += 64) {
        #pragma unroll
        for (int j = 0; j < 16; j += 4) {
            float4 v = *(const float4*)(ip + lrow * 512 + kc + lcol + j);
            ip_lds[lrow][lcol + j] = v.x; ip_lds[lrow][lcol + j + 1] = v.y;
            ip_lds[lrow][lcol + j + 2] = v.z; ip_lds[lrow][lcol + j + 3] = v.w;
            float4 u = *(const float4*)(h + lrow * 512 + kc + lcol + j);
            h_lds[lrow][lcol + j] = u.x; h_lds[lrow][lcol + j + 1] = u.y;
            h_lds[lrow][lcol + j + 2] = u.z; h_lds[lrow][lcol + j + 3] = u.w;
        }
        if (tid < 128) {
            int r = tid >> 4, c = (tid & 15) * 4;
            float4 v = *(const float4*)(Wp + (size_t)(o0 + r) * 512 + kc + c);
            wp_lds[r][c] = v.x; wp_lds[r][c + 1] = v.y; wp_lds[r][c + 2] = v.z; wp_lds[r][c + 3] = v.w;
        } else {
            int t2 = tid - 128;
            int r = t2 >> 4, c = (t2 & 15) * 4;
            float4 v = *(const float4*)(Wr + (size_t)(o0 + r) * 512 + kc + c);
            wr_lds[r][c] = v.x; wr_lds[r][c + 1] = v.y; wr_lds[r][c + 2] = v.z; wr_lds[r][c + 3] = v.w;
        }
        __syncthreads();
        #pragma unroll 4
        for (int k = 0; k < 64; ++k) {
            float wpv = wp_lds[oo][k], wrv = wr_lds[oo][k];
            acc0 += ip_lds[bb][k] * wpv + h_lds[bb][k] * wrv;
            acc1 += ip_lds[bb + 32][k] * wpv + h_lds[bb + 32][k] * wrv;
        }
        __syncthreads();
    }
    const int o = o0 + oo;
    float base = bp[o] + bq[o] + br[o];
    prq[bb * 512 + o] = acc0 + base;
    prq[(bb + 32) * 512 + o] = acc1 + base;
}

// ---------- kernel 2: fused Gq GEMM + tanh + w-reduction -> partial logits ----------
// m97 structure: 128x128 tile, 256 thr (4 waves of 64x64), BK=32, global_load_lds w=16.
// A fp32 tile (16 KB) swizzled via source; cvt->bf16 on read. B bf16 (8 KB) same scheme.
// Grid 4096 = 1024 m-blocks x 4 n-blocks; XCD-chunked remap keeps an m's 4 n-blocks
// adjacent on one XCD (A-panel L2 reuse). Epilogue atomicAdds 128 partial logits.
__global__ __launch_bounds__(256, 3) void k_gq(
        const float* __restrict__ iq, const unsigned short* __restrict__ Wq_bf,
        const float* __restrict__ prq, const float* __restrict__ wv,
        float* __restrict__ logits) {
    __shared__ float A_t[128][32];            // 16 KB, 16B-chunk swizzle: chunk ^= row&7
    __shared__ unsigned short B_t[128][32];   // 8 KB,  chunk ^= (row>>1)&3
    __shared__ float w_lds[128];
    __shared__ float prq_lds[128];
    __shared__ float red[2][128];

    const int tid = threadIdx.x;
    const int bid = blockIdx.x;
    const int orig = (bid & 7) * 512 + (bid >> 3);   // XCD-chunked (4096 % 8 == 0)
    const int m0 = (orig >> 2) * 128;
    const int n0 = (orig & 3) * 128;
    const int b = m0 >> 11;

    if (tid < 128) {
        w_lds[tid] = wv[n0 + tid];
        prq_lds[tid] = prq[b * 512 + n0 + tid];
    }

    const int lane = tid & 63;
    const int wave = tid >> 6;                // 0..3
    const int wm = wave >> 1;                 // 0..1 (m half)
    const int wn = wave & 1;                  // 0..1 (n half)
    const int r16 = lane & 15;
    const int cc = lane >> 4;                 // k-chunk

    // read-side swizzled offsets (lane-constant within the frag loops)
    const int ha0 = (((2 * cc) ^ (r16 & 7)) << 2);       // float index in A row
    const int ha1 = (((2 * cc + 1) ^ (r16 & 7)) << 2);
    const int bswz = ((cc ^ ((r16 >> 1) & 3)) << 3);     // ushort index in B row

    // staging sources (per-lane, pre-swizzled); dests are wave-uniform + lane*16B
    const float* asrc[4];
    #pragma unroll
    for (int r = 0; r < 4; ++r) {
        int t = r * 256 + tid;
        int row = t >> 3, s = t & 7;          // 8 x 16B chunks per 128B fp32 row
        asrc[r] = iq + (size_t)(m0 + row) * 512 + ((s ^ (row & 7)) << 2);
    }
    const unsigned short* bsrc[2];
    #pragma unroll
    for (int r = 0; r < 2; ++r) {
        int u = r * 256 + tid;
        int row = u >> 2, s = u & 3;          // 4 x 16B chunks per 64B bf16 row
        bsrc[r] = Wq_bf + (size_t)(n0 + row) * 512 + ((s ^ ((row >> 1) & 3)) << 3);
    }
    char* adst = (char*)A_t + wave * 1024;
    char* bdst = (char*)B_t + wave * 1024;

    f32x4 acc[4][4];
    #pragma unroll
    for (int i = 0; i < 4; ++i)
        #pragma unroll
        for (int j = 0; j < 4; ++j) acc[i][j] = (f32x4){0.f, 0.f, 0.f, 0.f};

    for (int k0 = 0; k0 < 512; k0 += 32) {
        gload_lds16(asrc[0] + k0, adst);
        gload_lds16(asrc[1] + k0, adst + 4096);
        gload_lds16(asrc[2] + k0, adst + 8192);
        gload_lds16(asrc[3] + k0, adst + 12288);
        gload_lds16(bsrc[0] + k0, bdst);
        gload_lds16(bsrc[1] + k0, bdst + 4096);
        __syncthreads();

        short8 af[4];
        #pragma unroll
        for (int mf = 0; mf < 4; ++mf) {
            const float* rp = &A_t[wm * 64 + mf * 16 + r16][0];
            f32x4 x0 = *(const f32x4*)(rp + ha0);
            f32x4 x1 = *(const f32x4*)(rp + ha1);
            ushort8v u;
            u[0] = f2bf(x0[0]); u[1] = f2bf(x0[1]); u[2] = f2bf(x0[2]); u[3] = f2bf(x0[3]);
            u[4] = f2bf(x1[0]); u[5] = f2bf(x1[1]); u[6] = f2bf(x1[2]); u[7] = f2bf(x1[3]);
            af[mf] = __builtin_bit_cast(short8, u);
        }
        #pragma unroll
        for (int nf = 0; nf < 4; ++nf) {
            short8 bfr = *(const short8*)&B_t[wn * 64 + nf * 16 + r16][bswz];
            #pragma unroll
            for (int mf = 0; mf < 4; ++mf)
                acc[mf][nf] = __builtin_amdgcn_mfma_f32_16x16x32_bf16(af[mf], bfr, acc[mf][nf], 0, 0, 0);
        }
        __syncthreads();
    }

    // epilogue: partial logit = sum over this block's 128 cols of w[c]*tanh(acc+prq[c])
    float part[4][4];
    #pragma unroll
    for (int mf = 0; mf < 4; ++mf)
        #pragma unroll
        for (int j = 0; j < 4; ++j) part[mf][j] = 0.f;

    #pragma unroll
    for (int nf = 0; nf < 4; ++nf) {
        int c = wn * 64 + nf * 16 + r16;
        float wc = w_lds[c];
        float pc = prq_lds[c];
        #pragma unroll
        for (int mf = 0; mf < 4; ++mf) {
            #pragma unroll
            for (int j = 0; j < 4; ++j) {
                float x = acc[mf][nf][j] + pc;
                float e = __expf(2.f * x);               // fast tanh: 1 - 2/(e^2x + 1)
                part[mf][j] += wc * (1.f - 2.f / (e + 1.f));
            }
        }
    }
    #pragma unroll
    for (int mf = 0; mf < 4; ++mf)
        #pragma unroll
        for (int j = 0; j < 4; ++j) {
            float v = part[mf][j];
            v += __shfl_xor(v, 1);
            v += __shfl_xor(v, 2);
            v += __shfl_xor(v, 4);
            v += __shfl_xor(v, 8);
            part[mf][j] = v;
        }
    if (r16 == 0) {
        #pragma unroll
        for (int mf = 0; mf < 4; ++mf)
            #pragma unroll
            for (int j = 0; j < 4; ++j)
                red[wn][wm * 64 + mf * 16 + cc * 4 + j] = part[mf][j];
    }
    __syncthreads();
    if (tid < 128)
        atomicAdd(&logits[m0 + tid], red[0][tid] + red[1][tid]);
}

// ---------- kernel 3: softmax stats per b; copy input_p -> out; zero z ----------
__global__ __launch_bounds__(256) void k_stats(const float* __restrict__ logits,
                                               const float* __restrict__ ip,
                                               float* __restrict__ out,
                                               float* __restrict__ stats) {
    const int b = blockIdx.x, tid = threadIdx.x;
    __shared__ float sm[256];
    float m = -1e30f;
    for (int i = tid; i < 2048; i += 256) m = fmaxf(m, logits[b * 2048 + i]);
    sm[tid] = m;
    __syncthreads();
    for (int s = 128; s > 0; s >>= 1) {
        if (tid < s) sm[tid] = fmaxf(sm[tid], sm[tid + s]);
        __syncthreads();
    }
    float bmax = sm[0];
    __syncthreads();
    float ssum = 0.f;
    for (int i = tid; i < 2048; i += 256) ssum += __expf(logits[b * 2048 + i] - bmax);
    sm[tid] = ssum;
    __syncthreads();
    for (int s = 128; s > 0; s >>= 1) {
        if (tid < s) sm[tid] += sm[tid + s];
        __syncthreads();
    }
    if (tid == 0) { stats[b * 2] = bmax; stats[b * 2 + 1] = sm[0]; }
    out[b * 1024 + tid] = ip[b * 512 + tid];
    out[b * 1024 + 256 + tid] = ip[b * 512 + 256 + tid];
    out[b * 1024 + 512 + tid] = 0.f;
    out[b * 1024 + 768 + tid] = 0.f;
}

// ---------- kernel 4: z[b,q] += sum_t alpha[b,t] * iq[b,t,q] ----------
#define TC 128
__global__ __launch_bounds__(256) void k_z(const float* __restrict__ logits,
                                           const float* __restrict__ stats,
                                           const float* __restrict__ iq,
                                           float* __restrict__ out) {
    const int blk = blockIdx.x;
    const int b = blk >> 4;
    const int c = blk & 15;
    const int tid = threadIdx.x;
    __shared__ float al[TC];
    const float bmax = stats[b * 2];
    const float inv = 1.f / stats[b * 2 + 1];
    if (tid < TC) al[tid] = __expf(logits[b * 2048 + c * TC + tid] - bmax) * inv;
    __syncthreads();
    const int q = tid * 2;
    float ax = 0.f, ay = 0.f;
    const float* base = iq + ((size_t)b * 2048 + (size_t)c * TC) * 512 + q;
    #pragma unroll 4
    for (int t = 0; t < TC; ++t) {
        float2 v = *(const float2*)(base + (size_t)t * 512);
        float a = al[t];
        ax += a * v.x;
        ay += a * v.y;
    }
    atomicAdd(&out[b * 1024 + 512 + q], ax);
    atomicAdd(&out[b * 1024 + 512 + q + 1], ay);
}

extern "C" void kernel_launch(void* const* d_in, const int* in_sizes, int n_in,
                              void* d_out, int out_size, void* d_ws, size_t ws_size,
                              hipStream_t stream) {
    const float* input_p = (const float*)d_in[0];
    const float* input_q = (const float*)d_in[1];
    const float* h_tm1   = (const float*)d_in[2];
    const float* Wp      = (const float*)d_in[3];
    const float* bp      = (const float*)d_in[4];
    const float* Wq      = (const float*)d_in[5];
    const float* bq      = (const float*)d_in[6];
    const float* Wr      = (const float*)d_in[7];
    const float* br      = (const float*)d_in[8];
    const float* wv      = (const float*)d_in[9];
    float* out = (float*)d_out;

    char* ws = (char*)d_ws;
    unsigned short* Wq_bf = (unsigned short*)ws;            // 512 KB
    float* prq    = (float*)(ws + 512 * 1024);              // 128 KB
    float* logits = (float*)(ws + 640 * 1024);              // 512 KB
    float* stats  = (float*)(ws + 1152 * 1024);             // 512 B

    k_zero<<<dim3(128), dim3(256), 0, stream>>>(logits);
    k_convert<<<dim3(128), dim3(256), 0, stream>>>(Wq, Wq_bf);
    k_prq<<<dim3(64), dim3(256), 0, stream>>>(input_p, h_tm1, Wp, Wr, bp, bq, br, prq);
    k_gq<<<dim3(4096), dim3(256), 0, stream>>>(input_q, Wq_bf, prq, wv, logits);
    k_stats<<<dim3(64), dim3(256), 0, stream>>>(logits, input_p, out, stats);
    k_z<<<dim3(64 * 16), dim3(256), 0, stream>>>(logits, stats, input_q, out);
}